// Round 6
// baseline (79.937 us; speedup 1.0000x reference)
//
#include <hip/hip_runtime.h>
#include <math.h>

#define BATCH 32
#define HW    (512*512)
#define N4    (HW/4)
#define BPB   128    // blocks per batch (4096 total; VGPR=40 -> 8 blocks/CU resident)
#define TPB   256

// workspace layout (bytes)
#define WS_SSUM   0      // double [B][12]
#define WS_DSUM   3072   // double [B][3]
#define WS_MU     3840   // float  [B][12]
#define WS_LCONST 5376   // float  [B]
#define WS_COUNTS 5504   // uint   [B][4]
#define WS_BYTES  6016

__device__ __forceinline__ float waveReduce(float v) {
#pragma unroll
  for (int off = 32; off > 0; off >>= 1) v += __shfl_down(v, off, 64);
  return v;
}

// Pass 1: per-batch counts[4] and ssum[seg=1..3][4]
__global__ __launch_bounds__(TPB) void k_sums(const float* __restrict__ emb,
                                              const int*   __restrict__ lab,
                                              double*      __restrict__ ssum,
                                              unsigned int* __restrict__ counts) {
  const int b   = blockIdx.y;
  const int tid = threadIdx.x;
  const float4* e0 = (const float4*)emb + (size_t)(b*4 + 0) * N4;
  const float4* e1 = (const float4*)emb + (size_t)(b*4 + 1) * N4;
  const float4* e2 = (const float4*)emb + (size_t)(b*4 + 2) * N4;
  const float4* e3 = (const float4*)emb + (size_t)(b*4 + 3) * N4;
  const int4*   lp = (const int4*)lab + (size_t)b * N4;

  float s[3][4] = {{0.f,0.f,0.f,0.f},{0.f,0.f,0.f,0.f},{0.f,0.f,0.f,0.f}};
  unsigned c[4] = {0u,0u,0u,0u};

  for (int i = blockIdx.x * TPB + tid; i < N4; i += BPB * TPB) {
    float4 v0 = e0[i], v1 = e1[i], v2 = e2[i], v3 = e3[i];
    int4 l4 = lp[i];
    const int ls[4] = {l4.x, l4.y, l4.z, l4.w};
    const float xs[4][4] = {{v0.x,v1.x,v2.x,v3.x},{v0.y,v1.y,v2.y,v3.y},
                            {v0.z,v1.z,v2.z,v3.z},{v0.w,v1.w,v2.w,v3.w}};
#pragma unroll
    for (int k = 0; k < 4; k++) {
      int l = ls[k];
      c[0] += (l == 0); c[1] += (l == 1); c[2] += (l == 2); c[3] += (l == 3);
#pragma unroll
      for (int seg = 0; seg < 3; seg++) {
        float m = (l == seg + 1) ? 1.0f : 0.0f;
#pragma unroll
        for (int d = 0; d < 4; d++) s[seg][d] += m * xs[k][d];
      }
    }
  }

  __shared__ float red[4][16];
  int wave = tid >> 6, lane = tid & 63;
  float vals[16];
#pragma unroll
  for (int seg = 0; seg < 3; seg++)
#pragma unroll
    for (int d = 0; d < 4; d++) vals[seg*4 + d] = s[seg][d];
#pragma unroll
  for (int k = 0; k < 4; k++) vals[12 + k] = (float)c[k];
#pragma unroll
  for (int v = 0; v < 16; v++) {
    float r = waveReduce(vals[v]);
    if (lane == 0) red[wave][v] = r;
  }
  __syncthreads();
  if (tid < 16) {
    float t = red[0][tid] + red[1][tid] + red[2][tid] + red[3][tid];
    if (tid < 12) atomicAdd(&ssum[b*12 + tid], (double)t);
    else          atomicAdd(&counts[b*4 + (tid - 12)], (unsigned)(t + 0.5f));
  }
}

// Tiny: mu, distance term (exact masking semantics), reg term
__global__ void k_mu(const double* __restrict__ ssum, const unsigned* __restrict__ counts,
                     float* __restrict__ muout, float* __restrict__ lconst) {
  int b = threadIdx.x;
  if (b >= BATCH) return;
  float mu[4][4];
#pragma unroll
  for (int c = 0; c < 4; c++) mu[0][c] = 0.f;
#pragma unroll
  for (int s = 1; s < 4; s++) {
    unsigned cnt = counts[b*4 + s];
    double cs = (cnt > 0) ? (double)cnt : 1.0;
#pragma unroll
    for (int c = 0; c < 4; c++) {
      float v = (float)(ssum[b*12 + (s-1)*4 + c] / cs);
      mu[s][c] = v;
      muout[b*12 + (s-1)*4 + c] = v;
    }
  }
  float mnsum = 0.f; int msum = 0;
#pragma unroll
  for (int i = 0; i < 4; i++) {
#pragma unroll
    for (int j = 0; j < 4; j++) {
      float sabs = 0.f, nsq = 0.f;
#pragma unroll
      for (int c = 0; c < 4; c++) {
        float bv = (mu[i][c] != 0.f) ? mu[j][c] : 0.f;
        float iv = (bv != 0.f) ? mu[i][c] : 0.f;
        float df = bv - iv;
        sabs += fabsf(df);
        nsq  += df * df;
      }
      if (sabs != 0.f) {
        msum += 1;
        float t = fmaxf(6.0f - sqrtf(nsq), 0.f);
        mnsum += t * t;
      }
    }
  }
  float l_dist = (msum > 0) ? (mnsum / (float)msum) : 0.f;
  float rs = 0.f;
#pragma unroll
  for (int s = 0; s < 4; s++) {
    float nsq = 0.f;
#pragma unroll
    for (int c = 0; c < 4; c++) nsq += mu[s][c] * mu[s][c];
    rs += sqrtf(nsq);
  }
  lconst[b] = l_dist + 0.001f * (rs * 0.25f);
}

// Pass 2: per-pixel hinge distance to own cluster mean (labels 1..3 only)
__global__ __launch_bounds__(TPB) void k_var(const float* __restrict__ emb,
                                             const int*   __restrict__ lab,
                                             const float* __restrict__ mu,
                                             double*      __restrict__ dsum) {
  const int b   = blockIdx.y;
  const int tid = threadIdx.x;
  const float4* e0 = (const float4*)emb + (size_t)(b*4 + 0) * N4;
  const float4* e1 = (const float4*)emb + (size_t)(b*4 + 1) * N4;
  const float4* e2 = (const float4*)emb + (size_t)(b*4 + 2) * N4;
  const float4* e3 = (const float4*)emb + (size_t)(b*4 + 3) * N4;
  const int4*   lp = (const int4*)lab + (size_t)b * N4;

  float m1v[4], m2v[4], m3v[4];
#pragma unroll
  for (int c = 0; c < 4; c++) {
    m1v[c] = mu[b*12 + 0 + c];
    m2v[c] = mu[b*12 + 4 + c];
    m3v[c] = mu[b*12 + 8 + c];
  }
  float a1 = 0.f, a2 = 0.f, a3 = 0.f;

  for (int i = blockIdx.x * TPB + tid; i < N4; i += BPB * TPB) {
    float4 v0 = e0[i], v1 = e1[i], v2 = e2[i], v3 = e3[i];
    int4 l4 = lp[i];
    const int ls[4] = {l4.x, l4.y, l4.z, l4.w};
    const float xs[4][4] = {{v0.x,v1.x,v2.x,v3.x},{v0.y,v1.y,v2.y,v3.y},
                            {v0.z,v1.z,v2.z,v3.z},{v0.w,v1.w,v2.w,v3.w}};
#pragma unroll
    for (int k = 0; k < 4; k++) {
      int l = ls[k];
      float m1 = (l == 1) ? 1.f : 0.f;
      float m2 = (l == 2) ? 1.f : 0.f;
      float m3 = (l == 3) ? 1.f : 0.f;
      float d0 = xs[k][0] - (m1*m1v[0] + m2*m2v[0] + m3*m3v[0]);
      float d1 = xs[k][1] - (m1*m1v[1] + m2*m2v[1] + m3*m3v[1]);
      float d2 = xs[k][2] - (m1*m1v[2] + m2*m2v[2] + m3*m3v[2]);
      float d3 = xs[k][3] - (m1*m1v[3] + m2*m2v[3] + m3*m3v[3]);
      float dsq = d0*d0 + d1*d1 + d2*d2 + d3*d3;
      float h = fmaxf(sqrtf(dsq) - 0.5f, 0.f);
      float hh = h * h;
      a1 += hh * m1; a2 += hh * m2; a3 += hh * m3;
    }
  }

  __shared__ float red[4][3];
  int wave = tid >> 6, lane = tid & 63;
  float vals[3] = {a1, a2, a3};
#pragma unroll
  for (int v = 0; v < 3; v++) {
    float r = waveReduce(vals[v]);
    if (lane == 0) red[wave][v] = r;
  }
  __syncthreads();
  if (tid < 3) {
    float t = red[0][tid] + red[1][tid] + red[2][tid] + red[3][tid];
    atomicAdd(&dsum[b*3 + tid], (double)t);
  }
}

// Final: l_var per batch, gate on npres, mean over batches
__global__ void k_final(const double* __restrict__ dsum, const unsigned* __restrict__ counts,
                        const float* __restrict__ lconst, float* __restrict__ out) {
  int tid = threadIdx.x;
  float loss = 0.f;
  if (tid < BATCH) {
    int npres = 0; float acc = 0.f;
#pragma unroll
    for (int s = 1; s < 4; s++) {
      unsigned cnt = counts[tid*4 + s];
      if (cnt > 0) { npres++; acc += (float)(dsum[tid*3 + (s-1)] / (double)cnt); }
    }
    float l_var = (npres > 0) ? acc / (float)npres : 0.f;
    loss = (npres > 0) ? (l_var + lconst[tid]) : 0.f;
  }
#pragma unroll
  for (int off = 32; off > 0; off >>= 1) loss += __shfl_down(loss, off, 64);
  if (tid == 0) out[0] = loss / (float)BATCH;
}

extern "C" void kernel_launch(void* const* d_in, const int* in_sizes, int n_in,
                              void* d_out, int out_size, void* d_ws, size_t ws_size,
                              hipStream_t stream) {
  const float* emb = (const float*)d_in[0];
  const int*   lab = (const int*)d_in[2];   // d_in[1] = y, unused by reference
  float* out = (float*)d_out;
  char* ws = (char*)d_ws;
  double*   ssum   = (double*)(ws + WS_SSUM);
  double*   dsum   = (double*)(ws + WS_DSUM);
  float*    muv    = (float*)(ws + WS_MU);
  float*    lconst = (float*)(ws + WS_LCONST);
  unsigned* counts = (unsigned*)(ws + WS_COUNTS);

  hipMemsetAsync(d_ws, 0, WS_BYTES, stream);

  dim3 grid(BPB, BATCH);
  k_sums<<<grid, TPB, 0, stream>>>(emb, lab, ssum, counts);
  k_mu  <<<1, 64, 0, stream>>>(ssum, counts, muv, lconst);
  k_var <<<grid, TPB, 0, stream>>>(emb, lab, muv, dsum);
  k_final<<<1, 64, 0, stream>>>(dsum, counts, lconst, out);
}

// Round 8
// 64.724 us; speedup vs baseline: 1.2350x; 1.2350x over previous
//
#include <hip/hip_runtime.h>
#include <math.h>

#define BATCH 32
#define HW    (512*512)
#define N4    (HW/4)
#define BPB   16     // blocks per batch (512 total)
#define TPB   256

typedef float f32x4 __attribute__((ext_vector_type(4)));
typedef int   i32x4 __attribute__((ext_vector_type(4)));

// workspace layout (bytes)
#define WS_SSUM   0      // double [B][12]
#define WS_DSUM   3072   // double [B][3]
#define WS_MU     3840   // float  [B][12]
#define WS_LCONST 5376   // float  [B]
#define WS_COUNTS 5504   // uint   [B][4]
#define WS_BYTES  6016

__device__ __forceinline__ float waveReduce(float v) {
#pragma unroll
  for (int off = 32; off > 0; off >>= 1) v += __shfl_down(v, off, 64);
  return v;
}

// Pass 1: per-batch counts[1..3] and ssum[seg=1..3][4]
__global__ __launch_bounds__(TPB) void k_sums(const float* __restrict__ emb,
                                              const int*   __restrict__ lab,
                                              double*      __restrict__ ssum,
                                              unsigned int* __restrict__ counts) {
  const int b   = blockIdx.y;
  const int tid = threadIdx.x;
  const f32x4* e0 = (const f32x4*)emb + (size_t)(b*4 + 0) * N4;
  const f32x4* e1 = (const f32x4*)emb + (size_t)(b*4 + 1) * N4;
  const f32x4* e2 = (const f32x4*)emb + (size_t)(b*4 + 2) * N4;
  const f32x4* e3 = (const f32x4*)emb + (size_t)(b*4 + 3) * N4;
  const i32x4* lp = (const i32x4*)lab + (size_t)b * N4;

  float s[3][4] = {{0.f,0.f,0.f,0.f},{0.f,0.f,0.f,0.f},{0.f,0.f,0.f,0.f}};
  unsigned c[3] = {0u,0u,0u};

  for (int i = blockIdx.x * TPB + tid; i < N4; i += BPB * TPB) {
    f32x4 v0 = __builtin_nontemporal_load(&e0[i]);
    f32x4 v1 = __builtin_nontemporal_load(&e1[i]);
    f32x4 v2 = __builtin_nontemporal_load(&e2[i]);
    f32x4 v3 = __builtin_nontemporal_load(&e3[i]);
    i32x4 l4 = __builtin_nontemporal_load(&lp[i]);
#pragma unroll
    for (int k = 0; k < 4; k++) {
      int l = l4[k];
      float x0 = v0[k], x1 = v1[k], x2 = v2[k], x3 = v3[k];
      c[0] += (l == 1); c[1] += (l == 2); c[2] += (l == 3);
#pragma unroll
      for (int seg = 0; seg < 3; seg++) {
        float m = (l == seg + 1) ? 1.0f : 0.0f;
        s[seg][0] += m * x0; s[seg][1] += m * x1;
        s[seg][2] += m * x2; s[seg][3] += m * x3;
      }
    }
  }

  __shared__ float red[4][15];
  int wave = tid >> 6, lane = tid & 63;
  float vals[15];
#pragma unroll
  for (int seg = 0; seg < 3; seg++)
#pragma unroll
    for (int d = 0; d < 4; d++) vals[seg*4 + d] = s[seg][d];
#pragma unroll
  for (int k = 0; k < 3; k++) vals[12 + k] = (float)c[k];
#pragma unroll
  for (int v = 0; v < 15; v++) {
    float r = waveReduce(vals[v]);
    if (lane == 0) red[wave][v] = r;
  }
  __syncthreads();
  if (tid < 15) {
    float t = red[0][tid] + red[1][tid] + red[2][tid] + red[3][tid];
    if (tid < 12) atomicAdd(&ssum[b*12 + tid], (double)t);
    else          atomicAdd(&counts[b*4 + (tid - 12) + 1], (unsigned)(t + 0.5f));
  }
}

// Tiny: mu, distance term (exact masking semantics), reg term
__global__ void k_mu(const double* __restrict__ ssum, const unsigned* __restrict__ counts,
                     float* __restrict__ muout, float* __restrict__ lconst) {
  int b = threadIdx.x;
  if (b >= BATCH) return;
  float mu[4][4];
#pragma unroll
  for (int c = 0; c < 4; c++) mu[0][c] = 0.f;
#pragma unroll
  for (int s = 1; s < 4; s++) {
    unsigned cnt = counts[b*4 + s];
    double cs = (cnt > 0) ? (double)cnt : 1.0;
#pragma unroll
    for (int c = 0; c < 4; c++) {
      float v = (float)(ssum[b*12 + (s-1)*4 + c] / cs);
      mu[s][c] = v;
      muout[b*12 + (s-1)*4 + c] = v;
    }
  }
  float mnsum = 0.f; int msum = 0;
#pragma unroll
  for (int i = 0; i < 4; i++) {
#pragma unroll
    for (int j = 0; j < 4; j++) {
      float sabs = 0.f, nsq = 0.f;
#pragma unroll
      for (int c = 0; c < 4; c++) {
        float bv = (mu[i][c] != 0.f) ? mu[j][c] : 0.f;
        float iv = (bv != 0.f) ? mu[i][c] : 0.f;
        float df = bv - iv;
        sabs += fabsf(df);
        nsq  += df * df;
      }
      if (sabs != 0.f) {
        msum += 1;
        float t = fmaxf(6.0f - sqrtf(nsq), 0.f);
        mnsum += t * t;
      }
    }
  }
  float l_dist = (msum > 0) ? (mnsum / (float)msum) : 0.f;
  float rs = 0.f;
#pragma unroll
  for (int s = 0; s < 4; s++) {
    float nsq = 0.f;
#pragma unroll
    for (int c = 0; c < 4; c++) nsq += mu[s][c] * mu[s][c];
    rs += sqrtf(nsq);
  }
  lconst[b] = l_dist + 0.001f * (rs * 0.25f);
}

// Pass 2: per-pixel hinge distance to own cluster mean (labels 1..3 only)
__global__ __launch_bounds__(TPB) void k_var(const float* __restrict__ emb,
                                             const int*   __restrict__ lab,
                                             const float* __restrict__ mu,
                                             double*      __restrict__ dsum) {
  const int b   = blockIdx.y;
  const int tid = threadIdx.x;
  const f32x4* e0 = (const f32x4*)emb + (size_t)(b*4 + 0) * N4;
  const f32x4* e1 = (const f32x4*)emb + (size_t)(b*4 + 1) * N4;
  const f32x4* e2 = (const f32x4*)emb + (size_t)(b*4 + 2) * N4;
  const f32x4* e3 = (const f32x4*)emb + (size_t)(b*4 + 3) * N4;
  const i32x4* lp = (const i32x4*)lab + (size_t)b * N4;

  float m1v[4], m2v[4], m3v[4];
#pragma unroll
  for (int c = 0; c < 4; c++) {
    m1v[c] = mu[b*12 + 0 + c];
    m2v[c] = mu[b*12 + 4 + c];
    m3v[c] = mu[b*12 + 8 + c];
  }
  float a1 = 0.f, a2 = 0.f, a3 = 0.f;

  for (int i = blockIdx.x * TPB + tid; i < N4; i += BPB * TPB) {
    f32x4 v0 = __builtin_nontemporal_load(&e0[i]);
    f32x4 v1 = __builtin_nontemporal_load(&e1[i]);
    f32x4 v2 = __builtin_nontemporal_load(&e2[i]);
    f32x4 v3 = __builtin_nontemporal_load(&e3[i]);
    i32x4 l4 = __builtin_nontemporal_load(&lp[i]);
#pragma unroll
    for (int k = 0; k < 4; k++) {
      int l = l4[k];
      float m1 = (l == 1) ? 1.f : 0.f;
      float m2 = (l == 2) ? 1.f : 0.f;
      float m3 = (l == 3) ? 1.f : 0.f;
      float d0 = v0[k] - (m1*m1v[0] + m2*m2v[0] + m3*m3v[0]);
      float d1 = v1[k] - (m1*m1v[1] + m2*m2v[1] + m3*m3v[1]);
      float d2 = v2[k] - (m1*m1v[2] + m2*m2v[2] + m3*m3v[2]);
      float d3 = v3[k] - (m1*m1v[3] + m2*m2v[3] + m3*m3v[3]);
      float dsq = d0*d0 + d1*d1 + d2*d2 + d3*d3;
      float h = fmaxf(sqrtf(dsq) - 0.5f, 0.f);
      float hh = h * h;
      a1 += hh * m1; a2 += hh * m2; a3 += hh * m3;
    }
  }

  __shared__ float red[4][3];
  int wave = tid >> 6, lane = tid & 63;
  float vals[3] = {a1, a2, a3};
#pragma unroll
  for (int v = 0; v < 3; v++) {
    float r = waveReduce(vals[v]);
    if (lane == 0) red[wave][v] = r;
  }
  __syncthreads();
  if (tid < 3) {
    float t = red[0][tid] + red[1][tid] + red[2][tid] + red[3][tid];
    atomicAdd(&dsum[b*3 + tid], (double)t);
  }
}

// Final: l_var per batch, gate on npres, mean over batches
__global__ void k_final(const double* __restrict__ dsum, const unsigned* __restrict__ counts,
                        const float* __restrict__ lconst, float* __restrict__ out) {
  int tid = threadIdx.x;
  float loss = 0.f;
  if (tid < BATCH) {
    int npres = 0; float acc = 0.f;
#pragma unroll
    for (int s = 1; s < 4; s++) {
      unsigned cnt = counts[tid*4 + s];
      if (cnt > 0) { npres++; acc += (float)(dsum[tid*3 + (s-1)] / (double)cnt); }
    }
    float l_var = (npres > 0) ? acc / (float)npres : 0.f;
    loss = (npres > 0) ? (l_var + lconst[tid]) : 0.f;
  }
#pragma unroll
  for (int off = 32; off > 0; off >>= 1) loss += __shfl_down(loss, off, 64);
  if (tid == 0) out[0] = loss / (float)BATCH;
}

extern "C" void kernel_launch(void* const* d_in, const int* in_sizes, int n_in,
                              void* d_out, int out_size, void* d_ws, size_t ws_size,
                              hipStream_t stream) {
  const float* emb = (const float*)d_in[0];
  const int*   lab = (const int*)d_in[2];   // d_in[1] = y, unused by reference
  float* out = (float*)d_out;
  char* ws = (char*)d_ws;
  double*   ssum   = (double*)(ws + WS_SSUM);
  double*   dsum   = (double*)(ws + WS_DSUM);
  float*    muv    = (float*)(ws + WS_MU);
  float*    lconst = (float*)(ws + WS_LCONST);
  unsigned* counts = (unsigned*)(ws + WS_COUNTS);

  (void)hipMemsetAsync(d_ws, 0, WS_BYTES, stream);

  dim3 grid(BPB, BATCH);
  k_sums<<<grid, TPB, 0, stream>>>(emb, lab, ssum, counts);
  k_mu  <<<1, 64, 0, stream>>>(ssum, counts, muv, lconst);
  k_var <<<grid, TPB, 0, stream>>>(emb, lab, muv, dsum);
  k_final<<<1, 64, 0, stream>>>(dsum, counts, lconst, out);
}